// Round 1
// baseline (423.104 us; speedup 1.0000x reference)
//
#include <hip/hip_runtime.h>

#define TPB 256

// LDS geometry
// att: attn plane, rows 0..63, cols -15..79 (halo zeroed), stride 95 (odd -> conflict-free)
// uni: union buffer. Phase A: x plane rows -2..65, cols -2..66, stride 69 (zero halo).
//      Phase B: t plane (horizontal-pass result), rows 0..63, stride 65.
#define ATT_STRIDE 95
#define ATT_SIZE   (64 * 95)
#define XS_STRIDE  69
#define UNI_SIZE   (68 * 69)
#define TS_STRIDE  65

template <int K>
__device__ __forceinline__ void branch_pass(const int tid,
                                            float* __restrict__ att,
                                            float* __restrict__ uni,
                                            const float* __restrict__ wl,
                                            const int whoff, const int wvoff,
                                            const int bhoff, const int bvoff,
                                            float* __restrict__ outblk) {
    constexpr int T = 2 * K + 1;
    constexpr int W = 16 + 2 * K;
    // ---- horizontal 1x(2K+1): t(i,j) = sum_d attn(i, j+d-K)*wh[d] + bh ----
    {
        const int i = tid >> 2;             // 0..63
        const int j0 = (tid & 3) << 4;      // 0,16,32,48
        float wr[T];
#pragma unroll
        for (int d = 0; d < T; ++d) wr[d] = wl[whoff + d];
        const float bh = wl[bhoff];
        float win[W];
#pragma unroll
        for (int d = 0; d < W; ++d)
            win[d] = att[i * ATT_STRIDE + (j0 - K + d + 15)];
        float acc[16];
#pragma unroll
        for (int jj = 0; jj < 16; ++jj) acc[jj] = bh;
#pragma unroll
        for (int d = 0; d < T; ++d) {
            const float w = wr[d];
#pragma unroll
            for (int jj = 0; jj < 16; ++jj) acc[jj] += win[jj + d] * w;
        }
#pragma unroll
        for (int jj = 0; jj < 16; ++jj)
            uni[i * TS_STRIDE + j0 + jj] = acc[jj];
    }
    __syncthreads();
    // ---- vertical (2K+1)x1: o(i,j) = sum_d t(i+d-K, j)*wv[d] + bv ----
    {
        const int j = tid & 63;
        const int i0 = (tid >> 6) << 4;     // wave-uniform: 0,16,32,48
        float wr[T];
#pragma unroll
        for (int d = 0; d < T; ++d) wr[d] = wl[wvoff + d];
        const float bv = wl[bvoff];
        float win[W];
#pragma unroll
        for (int d = 0; d < W; ++d) {
            const int r = i0 - K + d;
            const int rc = r < 0 ? 0 : (r > 63 ? 63 : r);   // safe address
            const float v = uni[rc * TS_STRIDE + j];
            win[d] = (r == rc) ? v : 0.0f;                  // zero padding
        }
        float acc[16];
#pragma unroll
        for (int ii = 0; ii < 16; ++ii) acc[ii] = bv;
#pragma unroll
        for (int d = 0; d < T; ++d) {
            const float w = wr[d];
#pragma unroll
            for (int ii = 0; ii < 16; ++ii) acc[ii] += win[ii + d] * w;
        }
        float* op = outblk + i0 * 64 + j;
#pragma unroll
        for (int ii = 0; ii < 16; ++ii) op[ii * 64] = acc[ii];
    }
    __syncthreads();   // t-plane may be overwritten by next branch
}

__global__ __launch_bounds__(TPB, 3)
void lka_fused_kernel(const float* __restrict__ x,
                      const float* __restrict__ w0,  const float* __restrict__ b0,
                      const float* __restrict__ w01, const float* __restrict__ b01,
                      const float* __restrict__ w02, const float* __restrict__ b02,
                      const float* __restrict__ w11, const float* __restrict__ b11,
                      const float* __restrict__ w12, const float* __restrict__ b12,
                      const float* __restrict__ w21, const float* __restrict__ b21,
                      const float* __restrict__ w22, const float* __restrict__ b22,
                      float* __restrict__ out) {
    __shared__ float att[ATT_SIZE];
    __shared__ float uni[UNI_SIZE];
    __shared__ float wl[144];

    const int tid = threadIdx.x;
    const int plane = blockIdx.x;       // b*128 + c
    const int b = plane >> 7;
    const int c = plane & 127;

    const float* xp = x + (size_t)plane * 4096;
    float* outb = out + ((size_t)b * 640 + (size_t)c) * 4096;

    // ---- phase 0a: zero LDS (halos must be 0), load per-channel weights ----
    for (int k = tid; k < ATT_SIZE; k += TPB) att[k] = 0.0f;
    for (int k = tid; k < UNI_SIZE; k += TPB) uni[k] = 0.0f;
    if (tid < 25)        wl[tid] = w0 [c * 25 + tid];
    else if (tid < 32)   wl[tid] = w01[c * 7  + tid - 25];
    else if (tid < 39)   wl[tid] = w02[c * 7  + tid - 32];
    else if (tid < 54)   wl[tid] = w11[c * 15 + tid - 39];
    else if (tid < 69)   wl[tid] = w12[c * 15 + tid - 54];
    else if (tid < 100)  wl[tid] = w21[c * 31 + tid - 69];
    else if (tid < 131)  wl[tid] = w22[c * 31 + tid - 100];
    else if (tid == 131) wl[131] = b0 [c];
    else if (tid == 132) wl[132] = b01[c];
    else if (tid == 133) wl[133] = b02[c];
    else if (tid == 134) wl[134] = b11[c];
    else if (tid == 135) wl[135] = b12[c];
    else if (tid == 136) wl[136] = b21[c];
    else if (tid == 137) wl[137] = b22[c];
    __syncthreads();

    // ---- phase 0b: load x plane -> LDS interior; free concat-copy to out block 0 ----
    {
        const float4* x4 = (const float4*)xp;
        float4* o4 = (float4*)outb;
#pragma unroll
        for (int s = 0; s < 4; ++s) {
            const int idx = tid + s * TPB;        // 0..1023 float4s
            const float4 v = x4[idx];
            o4[idx] = v;
            const int r = idx >> 4;               // row 0..63
            const int c0 = (idx & 15) << 2;       // col 0,4,..,60
            float* dst = &uni[(r + 2) * XS_STRIDE + (c0 + 2)];
            dst[0] = v.x; dst[1] = v.y; dst[2] = v.z; dst[3] = v.w;
        }
    }
    __syncthreads();

    // ---- phase 1: 5x5 depthwise conv + b0 -> out block 1 and att LDS ----
    {
        const int i = tid >> 2;
        const int j0 = (tid & 3) << 4;
        float wr[25];
#pragma unroll
        for (int d = 0; d < 25; ++d) wr[d] = wl[d];
        const float bias = wl[131];
        float acc[16];
#pragma unroll
        for (int jj = 0; jj < 16; ++jj) acc[jj] = bias;
#pragma unroll
        for (int a = 0; a < 5; ++a) {
            float win[20];
#pragma unroll
            for (int d = 0; d < 20; ++d)
                win[d] = uni[(i + a) * XS_STRIDE + (j0 + d)];  // x(i+a-2, j0+d-2) via halo offset
#pragma unroll
            for (int bb = 0; bb < 5; ++bb) {
                const float w = wr[a * 5 + bb];
#pragma unroll
                for (int jj = 0; jj < 16; ++jj) acc[jj] += win[jj + bb] * w;
            }
        }
        float* op = outb + 1 * 128 * 4096 + i * 64 + j0;
#pragma unroll
        for (int q = 0; q < 4; ++q)
            ((float4*)op)[q] = make_float4(acc[4 * q], acc[4 * q + 1], acc[4 * q + 2], acc[4 * q + 3]);
#pragma unroll
        for (int jj = 0; jj < 16; ++jj)
            att[i * ATT_STRIDE + (j0 + jj + 15)] = acc[jj];
    }
    __syncthreads();

    // ---- phase 2: three separable branches (reuse uni as t-plane) ----
    branch_pass<3 >(tid, att, uni, wl, 25, 32,  132, 133, outb + (size_t)2 * 128 * 4096);
    branch_pass<7 >(tid, att, uni, wl, 39, 54,  134, 135, outb + (size_t)3 * 128 * 4096);
    branch_pass<15>(tid, att, uni, wl, 69, 100, 136, 137, outb + (size_t)4 * 128 * 4096);
}

extern "C" void kernel_launch(void* const* d_in, const int* in_sizes, int n_in,
                              void* d_out, int out_size, void* d_ws, size_t ws_size,
                              hipStream_t stream) {
    const float* x   = (const float*)d_in[0];
    const float* w0  = (const float*)d_in[1];
    const float* b0  = (const float*)d_in[2];
    const float* w01 = (const float*)d_in[3];
    const float* b01 = (const float*)d_in[4];
    const float* w02 = (const float*)d_in[5];
    const float* b02 = (const float*)d_in[6];
    const float* w11 = (const float*)d_in[7];
    const float* b11 = (const float*)d_in[8];
    const float* w12 = (const float*)d_in[9];
    const float* b12 = (const float*)d_in[10];
    const float* w21 = (const float*)d_in[11];
    const float* b21 = (const float*)d_in[12];
    const float* w22 = (const float*)d_in[13];
    const float* b22 = (const float*)d_in[14];
    float* out = (float*)d_out;

    lka_fused_kernel<<<dim3(4096), dim3(TPB), 0, stream>>>(
        x, w0, b0, w01, b01, w02, b02, w11, b11, w12, b12, w21, b21, w22, b22, out);
}

// Round 2
// 420.380 us; speedup vs baseline: 1.0065x; 1.0065x over previous
//
#include <hip/hip_runtime.h>

#define TPB 256

// LDS geometry (all strides: multiple of 4 for b128 alignment, != 0 mod 32 per
// row-pair so wave access is <=2-way bank aliased, which is free on gfx950).
// att: attn plane. rows 0..63, stored col = c+16 in [0,100). Window needs
//      stored cols [1,95); halo zeroed once. stride 100 (100%32=4).
// uni: union buffer, 6528 floats.
//      Phase A (x): stored row = r+2 in [0,68), stored col = c+4 in [0,76). stride 76 (76%32=12).
//      Phase B (t): stored row = r+16 in [0,96), cols 0..63. stride 68 (68%32=4).
//      t row-halo (stored rows [0,16) and [80,96)) re-zeroed after conv5 reads x.
#define ATT_STRIDE 100
#define ATT_SIZE   (64 * 100)
#define XS_STRIDE  76
#define TS_STRIDE  68
#define UNI_SIZE   (96 * 68)

template <int K>
__device__ __forceinline__ void h_pass(const int tid, const float* __restrict__ att,
                                       float* __restrict__ uni, const float* __restrict__ wl,
                                       const int whoff, const int bhoff) {
    constexpr int T = 2 * K + 1;
    constexpr int S0 = (16 - K) & ~3;       // aligned load start (stored col - j0)
    constexpr int L4 = ((16 - K - S0) + 16 + 2 * K + 3) / 4;  // float4 count
    const int i = tid >> 2;
    const int j0 = (tid & 3) << 4;
    float wr[T];
#pragma unroll
    for (int d = 0; d < T; ++d) wr[d] = wl[whoff + d];
    const float bh = wl[bhoff];
    float raw[4 * L4];
#pragma unroll
    for (int k = 0; k < L4; ++k)
        *(float4*)&raw[4 * k] = *(const float4*)&att[i * ATT_STRIDE + j0 + S0 + 4 * k];
    float acc[16];
#pragma unroll
    for (int jj = 0; jj < 16; ++jj) acc[jj] = bh;
#pragma unroll
    for (int d = 0; d < T; ++d) {
        const float w = wr[d];
#pragma unroll
        for (int jj = 0; jj < 16; ++jj) acc[jj] += raw[jj + d + 1] * w;  // off = (16-K)-S0 = 1
    }
#pragma unroll
    for (int q = 0; q < 4; ++q)
        *(float4*)&uni[(i + 16) * TS_STRIDE + j0 + 4 * q] =
            make_float4(acc[4 * q], acc[4 * q + 1], acc[4 * q + 2], acc[4 * q + 3]);
}

template <int K>
__device__ __forceinline__ void v_pass(const int tid, const float* __restrict__ uni,
                                       const float* __restrict__ wl,
                                       const int wvoff, const int bvoff,
                                       float* __restrict__ outblk) {
    constexpr int T = 2 * K + 1;
    constexpr int W = 16 + 2 * K;
    const int j = tid & 63;
    const int i0 = (tid >> 6) << 4;         // wave-uniform 0,16,32,48
    float wr[T];
#pragma unroll
    for (int d = 0; d < T; ++d) wr[d] = wl[wvoff + d];
    const float bv = wl[bvoff];
    float win[W];
#pragma unroll
    for (int d = 0; d < W; ++d)
        win[d] = uni[(i0 - K + d + 16) * TS_STRIDE + j];   // halo rows are zero
    float acc[16];
#pragma unroll
    for (int ii = 0; ii < 16; ++ii) acc[ii] = bv;
#pragma unroll
    for (int d = 0; d < T; ++d) {
        const float w = wr[d];
#pragma unroll
        for (int ii = 0; ii < 16; ++ii) acc[ii] += win[ii + d] * w;
    }
    float* op = outblk + i0 * 64 + j;
#pragma unroll
    for (int ii = 0; ii < 16; ++ii) op[ii * 64] = acc[ii];
}

__global__ __launch_bounds__(TPB, 3)
void lka_fused_kernel(const float* __restrict__ x,
                      const float* __restrict__ w0,  const float* __restrict__ b0,
                      const float* __restrict__ w01, const float* __restrict__ b01,
                      const float* __restrict__ w02, const float* __restrict__ b02,
                      const float* __restrict__ w11, const float* __restrict__ b11,
                      const float* __restrict__ w12, const float* __restrict__ b12,
                      const float* __restrict__ w21, const float* __restrict__ b21,
                      const float* __restrict__ w22, const float* __restrict__ b22,
                      float* __restrict__ out) {
    __shared__ __align__(16) float att[ATT_SIZE];
    __shared__ __align__(16) float uni[UNI_SIZE];
    __shared__ __align__(16) float wl[144];

    const int tid = threadIdx.x;
    const int plane = blockIdx.x;       // b*128 + c
    const int b = plane >> 7;
    const int c = plane & 127;

    const float* xp = x + (size_t)plane * 4096;
    float* outb = out + ((size_t)b * 640 + (size_t)c) * 4096;

    // ---- phase 0a: vectorized zero of both planes; stage per-channel weights ----
    {
        const float4 z4 = make_float4(0.f, 0.f, 0.f, 0.f);
        float4* a4 = (float4*)att;
#pragma unroll
        for (int k = tid; k < ATT_SIZE / 4; k += TPB) a4[k] = z4;
        float4* u4 = (float4*)uni;
#pragma unroll
        for (int k = tid; k < UNI_SIZE / 4; k += TPB) u4[k] = z4;
    }
    if (tid < 25)        wl[tid] = w0 [c * 25 + tid];
    else if (tid < 32)   wl[tid] = w01[c * 7  + tid - 25];
    else if (tid < 39)   wl[tid] = w02[c * 7  + tid - 32];
    else if (tid < 54)   wl[tid] = w11[c * 15 + tid - 39];
    else if (tid < 69)   wl[tid] = w12[c * 15 + tid - 54];
    else if (tid < 100)  wl[tid] = w21[c * 31 + tid - 69];
    else if (tid < 131)  wl[tid] = w22[c * 31 + tid - 100];
    else if (tid == 131) wl[131] = b0 [c];
    else if (tid == 132) wl[132] = b01[c];
    else if (tid == 133) wl[133] = b02[c];
    else if (tid == 134) wl[134] = b11[c];
    else if (tid == 135) wl[135] = b12[c];
    else if (tid == 136) wl[136] = b21[c];
    else if (tid == 137) wl[137] = b22[c];
    __syncthreads();

    // ---- phase 0b: x plane -> LDS (b128) + free concat-copy to out block 0 ----
    {
        const float4* x4 = (const float4*)xp;
        float4* o4 = (float4*)outb;
#pragma unroll
        for (int s = 0; s < 4; ++s) {
            const int idx = tid + s * TPB;        // 0..1023 float4s
            const float4 v = x4[idx];
            o4[idx] = v;
            const int r = idx >> 4;               // row 0..63
            const int c0 = (idx & 15) << 2;       // col 0,4,..,60
            *(float4*)&uni[(r + 2) * XS_STRIDE + c0 + 4] = v;
        }
    }
    __syncthreads();

    // ---- phase 1: 5x5 depthwise conv + b0 -> out block 1 and att LDS ----
    {
        const int i = tid >> 2;
        const int j0 = (tid & 3) << 4;
        float wr[25];
#pragma unroll
        for (int d = 0; d < 25; ++d) wr[d] = wl[d];
        const float bias = wl[131];
        float acc[16];
#pragma unroll
        for (int jj = 0; jj < 16; ++jj) acc[jj] = bias;
#pragma unroll
        for (int a = 0; a < 5; ++a) {
            float raw[24];
#pragma unroll
            for (int k = 0; k < 6; ++k)
                *(float4*)&raw[4 * k] = *(const float4*)&uni[(i + a) * XS_STRIDE + j0 + 4 * k];
#pragma unroll
            for (int bb = 0; bb < 5; ++bb) {
                const float w = wr[a * 5 + bb];
#pragma unroll
                for (int jj = 0; jj < 16; ++jj) acc[jj] += raw[jj + bb + 2] * w;
            }
        }
        float* op = outb + (size_t)1 * 128 * 4096 + i * 64 + j0;
#pragma unroll
        for (int q = 0; q < 4; ++q) {
            const float4 v = make_float4(acc[4 * q], acc[4 * q + 1], acc[4 * q + 2], acc[4 * q + 3]);
            ((float4*)op)[q] = v;
            *(float4*)&att[i * ATT_STRIDE + j0 + 16 + 4 * q] = v;
        }
    }
    __syncthreads();

    // ---- phase 2a: H3 + re-zero t row-halo (x data is dead now) ----
    {
        const float4 z4 = make_float4(0.f, 0.f, 0.f, 0.f);
        float4* u4 = (float4*)uni;
#pragma unroll
        for (int k = tid; k < 272; k += TPB) u4[k] = z4;           // stored rows [0,16)
#pragma unroll
        for (int k = tid; k < 272; k += TPB) u4[1360 + k] = z4;    // stored rows [80,96)
    }
    h_pass<3>(tid, att, uni, wl, 25, 132);
    __syncthreads();
    v_pass<3>(tid, uni, wl, 32, 133, outb + (size_t)2 * 128 * 4096);
    __syncthreads();

    h_pass<7>(tid, att, uni, wl, 39, 134);
    __syncthreads();
    v_pass<7>(tid, uni, wl, 54, 135, outb + (size_t)3 * 128 * 4096);
    __syncthreads();

    h_pass<15>(tid, att, uni, wl, 69, 136);
    __syncthreads();
    v_pass<15>(tid, uni, wl, 100, 137, outb + (size_t)4 * 128 * 4096);
}

extern "C" void kernel_launch(void* const* d_in, const int* in_sizes, int n_in,
                              void* d_out, int out_size, void* d_ws, size_t ws_size,
                              hipStream_t stream) {
    const float* x   = (const float*)d_in[0];
    const float* w0  = (const float*)d_in[1];
    const float* b0  = (const float*)d_in[2];
    const float* w01 = (const float*)d_in[3];
    const float* b01 = (const float*)d_in[4];
    const float* w02 = (const float*)d_in[5];
    const float* b02 = (const float*)d_in[6];
    const float* w11 = (const float*)d_in[7];
    const float* b11 = (const float*)d_in[8];
    const float* w12 = (const float*)d_in[9];
    const float* b12 = (const float*)d_in[10];
    const float* w21 = (const float*)d_in[11];
    const float* b21 = (const float*)d_in[12];
    const float* w22 = (const float*)d_in[13];
    const float* b22 = (const float*)d_in[14];
    float* out = (float*)d_out;

    lka_fused_kernel<<<dim3(4096), dim3(TPB), 0, stream>>>(
        x, w0, b0, w01, b01, w02, b02, w11, b11, w12, b12, w21, b21, w22, b22, out);
}